// Round 15
// baseline (79.970 us; speedup 1.0000x reference)
//
#include <hip/hip_runtime.h>
#include <stdint.h>

#define HW   4096      // 64*64 spatial per batch
#define NEMB 1024

typedef float        f32x4  __attribute__((ext_vector_type(4)));
typedef short        bf16x8 __attribute__((ext_vector_type(8)));
typedef unsigned int u32x4  __attribute__((ext_vector_type(4)));

// pack 2 fp32 -> 2 bf16 in one u32 (lo = first operand)
#define CVTPK(D, LO, HI) asm("v_cvt_pk_bf16_f32 %0, %1, %2" : "=v"(D) : "v"(LO), "v"(HI))

// direct global->LDS DMA, 16B per lane (lane-linear dest)
__device__ __forceinline__ void gload_lds16(const void* g, void* l) {
    __builtin_amdgcn_global_load_lds(
        (const __attribute__((address_space(1))) void*)(uintptr_t)g,
        (__attribute__((address_space(3))) void*)(uintptr_t)l, 16, 0, 0);
}

// ---------------- init: zero counts/errsum, ens[k]=1+||e||^2, LDS-image codebook --
// embw: 8 tiles x 128 rows x 32 u32. Word addr of (tile, r, chunk c, pair p) =
// tile*4096 + r*32 + ((c ^ (r&7))<<2) + p   -> vq_main DMAs it LINEARLY.
__global__ __launch_bounds__(128) void vq_init(const float* __restrict__ emb,
                                               unsigned int* __restrict__ counts,
                                               float* __restrict__ errsum,
                                               float* __restrict__ ens,
                                               unsigned int* __restrict__ embw) {
    const int gid  = blockIdx.x * 128 + threadIdx.x;   // 0..2047
    const int k    = gid >> 1;                         // emb row
    const int half = gid & 1;                          // chunks half*4..half*4+3
    if (half == 0) counts[k] = 0u;
    if (gid == 0) *errsum = 0.0f;
    const float* e = emb + k * 64 + half * 32;
    unsigned int* dst = embw + (k >> 7) * 4096 + (k & 127) * 32;
    float nrm = 0.0f;
    #pragma unroll
    for (int ci = 0; ci < 4; ++ci) {
        const int c = half * 4 + ci;
        f32x4 v0 = *(const f32x4*)(e + ci * 8);
        f32x4 v1 = *(const f32x4*)(e + ci * 8 + 4);
        nrm += v0.x*v0.x + v0.y*v0.y + v0.z*v0.z + v0.w*v0.w
             + v1.x*v1.x + v1.y*v1.y + v1.z*v1.z + v1.w*v1.w;
        u32x4 w;
        CVTPK(w.x, v0.x, v0.y); CVTPK(w.y, v0.z, v0.w);
        CVTPK(w.z, v1.x, v1.y); CVTPK(w.w, v1.z, v1.w);
        *(u32x4*)&dst[(c ^ (k & 7)) << 2] = w;
    }
    float o = __shfl_xor(nrm, 1, 64);
    if (half == 0) ens[k] = 1.0f + (nrm + o);
}

// ---------------- main: MFMA screen, DMA double-buffered codebook ----------------
// grid 512 x 512 (2 blocks/CU, 16 waves/CU). Block: 128 samples.
// 8 k-tiles of 128 embs; et double buffer filled by global_load_lds (counted vmcnt).
__global__ __launch_bounds__(512, 4)
void vq_main(const float* __restrict__ z, const float* __restrict__ emb,
             const float* __restrict__ ens, const unsigned int* __restrict__ embw,
             float* __restrict__ out, unsigned int* __restrict__ counts,
             float* __restrict__ errsum)
{
    __shared__ __attribute__((aligned(16))) float z_lds[64 * 128];     // fp32 [d][x]
    __shared__ __attribute__((aligned(16))) unsigned int et0[4096];    // 16KB tile buf A
    __shared__ __attribute__((aligned(16))) unsigned int et1[4096];    // 16KB tile buf B
    __shared__ __attribute__((aligned(16))) float ens_lds[NEMB];
    __shared__ int   idx_sh[128];
    __shared__ float errw[8];

    const int t   = threadIdx.x;
    const int n0  = blockIdx.x * 128;
    const int bb  = n0 >> 12;
    const int hw0 = n0 & 4095;
    const float* zb = z + bb * (64 * HW) + hw0;

    // ---- prologue DMAs: z tile, ens, et tiles 0+1 ----
    #pragma unroll
    for (int it = 0; it < 4; ++it) {
        const int p = it * 512 + t;            // 16B chunk 0..2047
        gload_lds16(zb + (p >> 5) * HW + (p & 31) * 4, z_lds + p * 4);
    }
    if (t < 256) gload_lds16(ens + t * 4, ens_lds + t * 4);
    #pragma unroll
    for (int it = 0; it < 2; ++it) {           // tile 0 -> et0 (1024 chunks)
        const int p = it * 512 + t;
        gload_lds16(embw + p * 4, et0 + p * 4);
    }
    #pragma unroll
    for (int it = 0; it < 2; ++it) {           // tile 1 -> et1
        const int p = it * 512 + t;
        gload_lds16(embw + 4096 + p * 4, et1 + p * 4);
    }
    __syncthreads();   // compiler drains vmcnt+lgkm: z, ens, et0, et1 visible

    const int l   = t & 63;     // lane
    const int wv  = t >> 6;     // wave 0..7 -> samples wv*16..wv*16+15
    const int col = l & 15;     // A-row selector / emb index low bits
    const int bg  = l >> 4;     // k-group

    // ---- A fragments: z bf16, row=col, k-chunk rule matches B ----
    bf16x8 a0, a1;
    {
        const int xs = wv * 16 + col;
        u32x4 wa, wb;
        #pragma unroll
        for (int p2 = 0; p2 < 4; ++p2) {
            float lo = z_lds[(bg * 8 + p2 * 2    ) * 128 + xs];
            float hi = z_lds[(bg * 8 + p2 * 2 + 1) * 128 + xs];
            CVTPK(wa[p2], lo, hi);
            float lo2 = z_lds[(32 + bg * 8 + p2 * 2    ) * 128 + xs];
            float hi2 = z_lds[(32 + bg * 8 + p2 * 2 + 1) * 128 + xs];
            CVTPK(wb[p2], lo2, hi2);
        }
        a0 = __builtin_bit_cast(bf16x8, wa);
        a1 = __builtin_bit_cast(bf16x8, wb);
    }

    const int slot0 = (bg ^ (col & 7)) << 2;   // u32 offset of chunk bg in row col
    const int rowoff = col * 32;
    const float* ensp = ens_lds + col;

    unsigned int mkey[4] = {~0u, ~0u, ~0u, ~0u};

    #pragma unroll 2
    for (int kt = 0; kt < 8; ++kt) {
        const unsigned int* etb = (kt & 1) ? et1 : et0;
        const unsigned int* ep0 = etb + rowoff + slot0;
        const unsigned int* ep1 = etb + rowoff + (slot0 ^ 16);

        #pragma unroll
        for (int i = 0; i < 8; ++i) {
            u32x4 bw0 = *(const u32x4*)(ep0 + i * 512);
            u32x4 bw1 = *(const u32x4*)(ep1 + i * 512);
            float en1 = ensp[kt * 128 + i * 16];
            f32x4 cc = {0.0f, 0.0f, 0.0f, 0.0f};
            cc = __builtin_amdgcn_mfma_f32_16x16x32_bf16(a0, __builtin_bit_cast(bf16x8, bw0), cc, 0, 0, 0);
            cc = __builtin_amdgcn_mfma_f32_16x16x32_bf16(a1, __builtin_bit_cast(bf16x8, bw1), cc, 0, 0, 0);
            const unsigned int kg = (unsigned int)(kt * 128 + i * 16 + col);
            #pragma unroll
            for (int j = 0; j < 4; ++j) {
                float s = fmaf(-2.0f, cc[j], en1);          // 1 + ||e||^2 - 2 z.e
                unsigned int key = (__builtin_bit_cast(unsigned int, s) & 0xFFFFFC00u) | kg;
                mkey[j] = mkey[j] < key ? mkey[j] : key;
            }
        }

        if (kt < 7) {
            __syncthreads();   // all waves done reading etb (tile kt)
            if (kt < 6) {      // refill etb with tile kt+2 (async)
                unsigned int* wbuf = (kt & 1) ? et1 : et0;
                const unsigned int* src = embw + (kt + 2) * 4096;
                #pragma unroll
                for (int it = 0; it < 2; ++it) {
                    const int p = it * 512 + t;
                    gload_lds16(src + p * 4, wbuf + p * 4);
                }
                // wait only for tile kt+1's DMA (issued last iter; had a full
                // compute phase to land) -- keep the 2 just-issued in flight
                asm volatile("s_waitcnt vmcnt(2)" ::: "memory");
            } else {
                asm volatile("s_waitcnt vmcnt(0)" ::: "memory");
            }
            __syncthreads();   // cross-wave publish: tile kt+1 readable
        }
    }

    // ---- reduce argmin across the 16 cols (lanes sharing bg) ----
    #pragma unroll
    for (int j = 0; j < 4; ++j) {
        #pragma unroll
        for (int m = 1; m <= 8; m <<= 1) {
            unsigned int o = (unsigned int)__shfl_xor((int)mkey[j], m, 64);
            mkey[j] = mkey[j] < o ? mkey[j] : o;
        }
    }
    if (col == 0) {
        #pragma unroll
        for (int j = 0; j < 4; ++j)
            idx_sh[wv * 16 + bg * 4 + j] = (int)(mkey[j] & 1023u);  // C row = 4*bg + j
    }
    __syncthreads();

    // ---- histogram ----
    if (t < 128) atomicAdd(&counts[idx_sh[t]], 1u);

    // ---- epilogue: out = z + (e - z), exact fp32 error for chosen code ----
    float part = 0.0f;
    {
        const int x  = t & 127;
        const int cg = t >> 7;     // 0..3 -> channels cg*16..+15
        const int idx = idx_sh[x];
        const float* er = emb + idx * 64;
        float* ob = out + bb * (64 * HW) + hw0 + x;
        #pragma unroll
        for (int cq = 0; cq < 4; ++cq) {
            const int c = cg * 16 + cq * 4;
            f32x4 e4 = *(const f32x4*)&er[c];
            float z0 = z_lds[(c+0) * 128 + x];
            float z1 = z_lds[(c+1) * 128 + x];
            float z2 = z_lds[(c+2) * 128 + x];
            float z3 = z_lds[(c+3) * 128 + x];
            ob[(c+0) * HW] = z0 + (e4.x - z0);
            ob[(c+1) * HW] = z1 + (e4.y - z1);
            ob[(c+2) * HW] = z2 + (e4.z - z2);
            ob[(c+3) * HW] = z3 + (e4.w - z3);
            float d0 = z0 - e4.x, d1 = z1 - e4.y, d2 = z2 - e4.z, d3 = z3 - e4.w;
            part = fmaf(d0, d0, part); part = fmaf(d1, d1, part);
            part = fmaf(d2, d2, part); part = fmaf(d3, d3, part);
        }
    }
    {
        float s = part;
        #pragma unroll
        for (int off = 32; off >= 1; off >>= 1) s += __shfl_down(s, off, 64);
        if (l == 0) atomicAdd(errsum, s);
    }
}

// ---------------- finalize: scalars ----------------
__global__ __launch_bounds__(256) void vq_fin(const unsigned int* __restrict__ counts,
                                              const float* __restrict__ errsum,
                                              float* __restrict__ scal)
{
    __shared__ float part[4];
    const int t = threadIdx.x;
    float s = 0.0f;
    for (int k = t; k < NEMB; k += 256) {
        float p = (float)counts[k] * (1.0f / 65536.0f);
        s += p * logf(p + 1e-10f);
    }
    #pragma unroll
    for (int off = 32; off >= 1; off >>= 1) s += __shfl_down(s, off, 64);
    if ((t & 63) == 0) part[t >> 6] = s;
    __syncthreads();
    if (t == 0) {
        float tot = (part[0] + part[1]) + (part[2] + part[3]);
        float es  = *errsum;
        scal[0] = 1.25f * (es * (1.0f / 4194304.0f));  // loss = 1.25 * mse
        scal[1] = expf(-tot);                          // perplexity
        scal[2] = es * (1.0f / 65536.0f);              // avg_error
    }
}

extern "C" void kernel_launch(void* const* d_in, const int* in_sizes, int n_in,
                              void* d_out, int out_size, void* d_ws, size_t ws_size,
                              hipStream_t stream) {
    const float* z   = (const float*)d_in[0];
    const float* emb = (const float*)d_in[1];
    float* out = (float*)d_out;
    unsigned int* counts = (unsigned int*)d_ws;
    float* errsum = (float*)((char*)d_ws + 4096);
    float* ens    = (float*)((char*)d_ws + 8192);
    unsigned int* embw = (unsigned int*)((char*)d_ws + 16384);   // 128 KB LDS-image

    vq_init<<<16, 128, 0, stream>>>(emb, counts, errsum, ens, embw);
    vq_main<<<512, 512, 0, stream>>>(z, emb, ens, embw, out, counts, errsum);
    vq_fin<<<1, 256, 0, stream>>>(counts, errsum, out + 4194304);
}

// Round 16
// 44.823 us; speedup vs baseline: 1.7842x; 1.7842x over previous
//
#include <hip/hip_runtime.h>
#include <stdint.h>

#define HW   4096      // 64*64 spatial per batch
#define NEMB 1024

typedef float        f32x4  __attribute__((ext_vector_type(4)));
typedef short        bf16x8 __attribute__((ext_vector_type(8)));
typedef unsigned int u32x4  __attribute__((ext_vector_type(4)));

// pack 2 fp32 -> 2 bf16 in one u32 (lo = first operand)
#define CVTPK(D, LO, HI) asm("v_cvt_pk_bf16_f32 %0, %1, %2" : "=v"(D) : "v"(LO), "v"(HI))

// direct global->LDS DMA, 16B per lane
__device__ __forceinline__ void gload_lds16(const float* g, float* l) {
    __builtin_amdgcn_global_load_lds(
        (const __attribute__((address_space(1))) void*)(uintptr_t)g,
        (__attribute__((address_space(3))) void*)(uintptr_t)l, 16, 0, 0);
}

// ---------------- main: MFMA distance screen + fused argmin + exact epilogue -------
// grid 512 x 512 (2 blocks/CU, 16 waves/CU). Block: 128 samples.
// Wave: 16 samples x all 1024 embs (4 k-tiles of 256 staged bf16 in LDS).
// ens (1+||e||^2) computed FREE during staging from in-register fp32 rows.
__global__ __launch_bounds__(512, 4)
void vq_main(const float* __restrict__ z, const float* __restrict__ emb,
             float* __restrict__ out, unsigned int* __restrict__ counts,
             float* __restrict__ errsum)
{
    __shared__ __attribute__((aligned(16))) float z_lds[64 * 128];   // fp32 [d][x]
    __shared__ __attribute__((aligned(16))) unsigned int et_w[256 * 32]; // bf16 tile, row r: slot s = chunk s^(r&7)
    __shared__ __attribute__((aligned(16))) float ens_lds[256];      // per-tile 1+||e||^2
    __shared__ int   idx_sh[128];
    __shared__ float errp[512];

    const int t   = threadIdx.x;
    const int n0  = blockIdx.x * 128;
    const int bb  = n0 >> 12;
    const int hw0 = n0 & 4095;
    const float* zb = z + bb * (64 * HW) + hw0;

    // ---- DMA z tile fp32 [d][128] ----
    #pragma unroll
    for (int it = 0; it < 4; ++it) {
        const int p = it * 512 + t;            // 16B chunk 0..2047
        gload_lds16(zb + (p >> 5) * HW + (p & 31) * 4, z_lds + p * 4);
    }

    // ---- stage et tile 0: fp32 load -> bf16 cvt -> swizzled ds_write + free norms ----
    #pragma unroll
    for (int it = 0; it < 4; ++it) {
        const int q = it * 512 + t;            // bf16 16B chunk 0..2047
        const int r = q >> 3, c = q & 7;
        const float* s2 = emb + r * 64 + c * 8;
        f32x4 e0 = *(const f32x4*)s2;
        f32x4 e1 = *(const f32x4*)(s2 + 4);
        u32x4 v;
        CVTPK(v.x, e0.x, e0.y); CVTPK(v.y, e0.z, e0.w);
        CVTPK(v.z, e1.x, e1.y); CVTPK(v.w, e1.z, e1.w);
        *(u32x4*)&et_w[r * 32 + ((c ^ (r & 7)) << 2)] = v;
        // row-norm partial: 8 lanes (c=0..7) share row r
        float pn = (e0.x*e0.x + e0.y*e0.y) + (e0.z*e0.z + e0.w*e0.w)
                 + (e1.x*e1.x + e1.y*e1.y) + (e1.z*e1.z + e1.w*e1.w);
        pn += __shfl_xor(pn, 1, 64);
        pn += __shfl_xor(pn, 2, 64);
        pn += __shfl_xor(pn, 4, 64);
        if (c == 0) ens_lds[r] = 1.0f + pn;
    }
    __syncthreads();   // z_lds + et tile0 + ens tile0 visible

    const int l   = t & 63;     // lane
    const int wv  = t >> 6;     // wave 0..7 -> samples wv*16..wv*16+15
    const int col = l & 15;     // A-row selector (input) / C col = emb (output)
    const int bg  = l >> 4;     // k-group

    // ---- A fragments: z bf16, row=col, k = 8*bg + e (same rule as B) ----
    bf16x8 a0, a1;
    {
        const int xs = wv * 16 + col;
        u32x4 wa, wb;
        #pragma unroll
        for (int p2 = 0; p2 < 4; ++p2) {
            float lo = z_lds[(bg * 8 + p2 * 2    ) * 128 + xs];
            float hi = z_lds[(bg * 8 + p2 * 2 + 1) * 128 + xs];
            CVTPK(wa[p2], lo, hi);
            float lo2 = z_lds[(32 + bg * 8 + p2 * 2    ) * 128 + xs];
            float hi2 = z_lds[(32 + bg * 8 + p2 * 2 + 1) * 128 + xs];
            CVTPK(wb[p2], lo2, hi2);
        }
        a0 = __builtin_bit_cast(bf16x8, wa);
        a1 = __builtin_bit_cast(bf16x8, wb);
    }

    const int slot0 = bg ^ (col & 7);
    const unsigned int* ep0 = et_w + col * 32 + slot0 * 4;
    const unsigned int* ep1 = et_w + col * 32 + (slot0 ^ 4) * 4;
    const float* ensp = ens_lds + col;

    unsigned int mkey[4] = {~0u, ~0u, ~0u, ~0u};

    #pragma unroll
    for (int kt = 0; kt < 4; ++kt) {
        // T14: prefetch next tile's fp32 into regs (consumed after barrier)
        f32x4 pf[8];
        if (kt < 3) {
            const float* src = emb + (kt + 1) * 256 * 64;
            #pragma unroll
            for (int it = 0; it < 4; ++it) {
                const int q = it * 512 + t;
                const float* s2 = src + (q >> 3) * 64 + (q & 7) * 8;
                pf[it * 2]     = *(const f32x4*)s2;
                pf[it * 2 + 1] = *(const f32x4*)(s2 + 4);
            }
        }

        #pragma unroll
        for (int i = 0; i < 16; ++i) {
            u32x4 bw0 = *(const u32x4*)(ep0 + i * 512);
            u32x4 bw1 = *(const u32x4*)(ep1 + i * 512);
            float en1 = ensp[i * 16];
            f32x4 cc = {0.0f, 0.0f, 0.0f, 0.0f};
            cc = __builtin_amdgcn_mfma_f32_16x16x32_bf16(a0, __builtin_bit_cast(bf16x8, bw0), cc, 0, 0, 0);
            cc = __builtin_amdgcn_mfma_f32_16x16x32_bf16(a1, __builtin_bit_cast(bf16x8, bw1), cc, 0, 0, 0);
            const unsigned int kg = (unsigned int)(kt * 256 + i * 16 + col);
            #pragma unroll
            for (int j = 0; j < 4; ++j) {
                float s = fmaf(-2.0f, cc[j], en1);          // 1 + ||e||^2 - 2 z.e
                unsigned int key = (__builtin_bit_cast(unsigned int, s) & 0xFFFFFC00u) | kg;
                mkey[j] = mkey[j] < key ? mkey[j] : key;    // strict-first + idx tie-break
            }
        }

        __syncthreads();   // all waves done reading et[kt] + ens[kt]
        if (kt < 3) {
            #pragma unroll
            for (int it = 0; it < 4; ++it) {
                const int q = it * 512 + t;
                const int r = q >> 3, c = q & 7;
                u32x4 v;
                CVTPK(v.x, pf[it*2].x,   pf[it*2].y);
                CVTPK(v.y, pf[it*2].z,   pf[it*2].w);
                CVTPK(v.z, pf[it*2+1].x, pf[it*2+1].y);
                CVTPK(v.w, pf[it*2+1].z, pf[it*2+1].w);
                *(u32x4*)&et_w[r * 32 + ((c ^ (r & 7)) << 2)] = v;
                float pn = (pf[it*2].x*pf[it*2].x + pf[it*2].y*pf[it*2].y)
                         + (pf[it*2].z*pf[it*2].z + pf[it*2].w*pf[it*2].w)
                         + (pf[it*2+1].x*pf[it*2+1].x + pf[it*2+1].y*pf[it*2+1].y)
                         + (pf[it*2+1].z*pf[it*2+1].z + pf[it*2+1].w*pf[it*2+1].w);
                pn += __shfl_xor(pn, 1, 64);
                pn += __shfl_xor(pn, 2, 64);
                pn += __shfl_xor(pn, 4, 64);
                if (c == 0) ens_lds[r] = 1.0f + pn;
            }
            __syncthreads();   // et[kt+1] + ens[kt+1] ready
        }
    }

    // ---- reduce argmin across the 16 cols (lanes sharing bg) ----
    #pragma unroll
    for (int j = 0; j < 4; ++j) {
        #pragma unroll
        for (int m = 1; m <= 8; m <<= 1) {
            unsigned int o = (unsigned int)__shfl_xor((int)mkey[j], m, 64);
            mkey[j] = mkey[j] < o ? mkey[j] : o;
        }
    }
    if (col == 0) {
        #pragma unroll
        for (int j = 0; j < 4; ++j)
            idx_sh[wv * 16 + bg * 4 + j] = (int)(mkey[j] & 1023u);  // C row = 4*bg + j
    }
    __syncthreads();

    // ---- histogram ----
    if (t < 128) atomicAdd(&counts[idx_sh[t]], 1u);

    // ---- epilogue: out = z + (e - z), exact fp32 error for chosen code ----
    {
        const int x  = t & 127;
        const int cg = t >> 7;     // 0..3 -> channels cg*16..+15
        const int idx = idx_sh[x];
        const float* er = emb + idx * 64;
        float* ob = out + bb * (64 * HW) + hw0 + x;
        float part = 0.0f;
        #pragma unroll
        for (int cq = 0; cq < 4; ++cq) {
            const int c = cg * 16 + cq * 4;
            f32x4 e4 = *(const f32x4*)&er[c];
            float z0 = z_lds[(c+0) * 128 + x];
            float z1 = z_lds[(c+1) * 128 + x];
            float z2 = z_lds[(c+2) * 128 + x];
            float z3 = z_lds[(c+3) * 128 + x];
            ob[(c+0) * HW] = z0 + (e4.x - z0);
            ob[(c+1) * HW] = z1 + (e4.y - z1);
            ob[(c+2) * HW] = z2 + (e4.z - z2);
            ob[(c+3) * HW] = z3 + (e4.w - z3);
            float d0 = z0 - e4.x, d1 = z1 - e4.y, d2 = z2 - e4.z, d3 = z3 - e4.w;
            part = fmaf(d0, d0, part); part = fmaf(d1, d1, part);
            part = fmaf(d2, d2, part); part = fmaf(d3, d3, part);
        }
        errp[t] = part;
    }
    __syncthreads();
    if (t < 128) {
        float s = (errp[t] + errp[t + 128]) + (errp[t + 256] + errp[t + 384]);
        #pragma unroll
        for (int off = 32; off >= 1; off >>= 1) s += __shfl_down(s, off, 64);
        if ((t & 63) == 0) atomicAdd(errsum, s);
    }
}

// ---------------- finalize: scalars ----------------
__global__ __launch_bounds__(256) void vq_fin(const unsigned int* __restrict__ counts,
                                              const float* __restrict__ errsum,
                                              float* __restrict__ scal)
{
    __shared__ float part[4];
    const int t = threadIdx.x;
    float s = 0.0f;
    for (int k = t; k < NEMB; k += 256) {
        float p = (float)counts[k] * (1.0f / 65536.0f);
        s += p * logf(p + 1e-10f);
    }
    #pragma unroll
    for (int off = 32; off >= 1; off >>= 1) s += __shfl_down(s, off, 64);
    if ((t & 63) == 0) part[t >> 6] = s;
    __syncthreads();
    if (t == 0) {
        float tot = (part[0] + part[1]) + (part[2] + part[3]);
        float es  = *errsum;
        scal[0] = 1.25f * (es * (1.0f / 4194304.0f));  // loss = 1.25 * mse
        scal[1] = expf(-tot);                          // perplexity
        scal[2] = es * (1.0f / 65536.0f);              // avg_error
    }
}

extern "C" void kernel_launch(void* const* d_in, const int* in_sizes, int n_in,
                              void* d_out, int out_size, void* d_ws, size_t ws_size,
                              hipStream_t stream) {
    const float* z   = (const float*)d_in[0];
    const float* emb = (const float*)d_in[1];
    float* out = (float*)d_out;
    unsigned int* counts = (unsigned int*)d_ws;
    float* errsum = (float*)((char*)d_ws + 4096);

    // zero counts + errsum via a memset node (graph-capturable, replaces vq_init)
    hipMemsetAsync(d_ws, 0, 8192, stream);
    vq_main<<<512, 512, 0, stream>>>(z, emb, out, counts, errsum);
    vq_fin<<<1, 256, 0, stream>>>(counts, errsum, out + 4194304);
}